// Round 6
// baseline (58.076 us; speedup 1.0000x reference)
//
#include <hip/hip_runtime.h>

typedef float f32x2 __attribute__((ext_vector_type(2)));
typedef float f32x4 __attribute__((ext_vector_type(4)));
typedef short short8 __attribute__((ext_vector_type(8)));  // 8 x bf16 bits

static __device__ __forceinline__ unsigned short f2bf(float f) {
    __bf16 h = (__bf16)f;
    return __builtin_bit_cast(unsigned short, h);
}

// ---------------------------------------------------------------------------
// Kernel A: contract TT cores into dense TRANSPOSED bf16 weights.
//   WdT[j][i] = Wd[i][j],  j in [0,64)  (z-col), i in [0,1024) (x-dim)
//   WuT[d][k] = Wu[k][d],  d in [0,1024) (y-col), k in [0,64)  (z-dim)
// ---------------------------------------------------------------------------
__global__ __launch_bounds__(256) void tt_build_w_kernel(
    const float* __restrict__ d1, const float* __restrict__ d2, const float* __restrict__ d3,
    const float* __restrict__ u1, const float* __restrict__ u2, const float* __restrict__ u3,
    unsigned short* __restrict__ WdT, unsigned short* __restrict__ WuT)
{
    int t = blockIdx.x * 256 + threadIdx.x;
    if (t < 65536) {
        int j = t >> 10, i = t & 1023;
        int i1 = i >> 7, i2 = (i >> 3) & 15, i3 = i & 7;
        int j1 = j >> 4, j2 = (j >> 2) & 3, j3 = j & 3;
        float t3[8];
#pragma unroll
        for (int b = 0; b < 8; ++b) t3[b] = d3[(b * 8 + i3) * 4 + j3];
        float wsum = 0.f;
#pragma unroll
        for (int a = 0; a < 8; ++a) {
            float va = d1[(i1 * 4 + j1) * 8 + a];
            const float* p2 = d2 + ((a * 16 + i2) * 4 + j2) * 8;
            float wa = 0.f;
#pragma unroll
            for (int b = 0; b < 8; ++b) wa = fmaf(p2[b], t3[b], wa);
            wsum = fmaf(va, wa, wsum);
        }
        WdT[j * 1024 + i] = f2bf(wsum);
    } else {
        int t2 = t - 65536;
        int d = t2 >> 6, k = t2 & 63;
        int k1 = k >> 4, k2 = (k >> 2) & 3, k3 = k & 3;
        int o1 = d >> 7, o2 = (d >> 3) & 15, o3 = d & 7;
        float t3[8];
#pragma unroll
        for (int b = 0; b < 8; ++b) t3[b] = u3[(b * 4 + k3) * 8 + o3];
        float wsum = 0.f;
#pragma unroll
        for (int a = 0; a < 8; ++a) {
            float va = u1[(k1 * 8 + o1) * 8 + a];
            const float* p2 = u2 + ((a * 4 + k2) * 16 + o2) * 8;
            float wa = 0.f;
#pragma unroll
            for (int b = 0; b < 8; ++b) wa = fmaf(p2[b], t3[b], wa);
            wsum = fmaf(va, wa, wsum);
        }
        WuT[d * 64 + k] = f2bf(wsum);
    }
}

// ---------------------------------------------------------------------------
// Main kernel: y = relu(x @ Wd + bd) @ Wu + bu via bf16 MFMA (16x16x32).
// r5 structure; CHANGE: the 16 x dwordx4 loads are INLINE ASM (volatile,
// literal offsets off one base) so they cannot be sunk/shrunk by ISel or
// MachineSink -> 16 KB per wave genuinely in flight (r2-r5 all collapsed
// to ~2 outstanding loads; VGPR 24-64 proved it). s_waitcnt vmcnt(0) +
// sched_barrier(0) per guide rule 18 before consuming.
// Fragment layouts (verified r1/r2): A/B lane holds 8 contiguous k at
// row/col = lane&15, kbase=(lane>>4)*8. C/D: col=lane&15, row=(lane>>4)*4+reg.
// ---------------------------------------------------------------------------
__global__ __launch_bounds__(256) void tt_main_kernel(
    const float* __restrict__ x, const unsigned short* __restrict__ WdT,
    const unsigned short* __restrict__ WuT, const float* __restrict__ bd,
    const float* __restrict__ bu, float* __restrict__ y)
{
    __shared__ float red[4][1024];            // conflict-free r2 layout
    __shared__ unsigned short zlds[16 * 80];  // [m][j] bf16, stride 80
    const int t = threadIdx.x;
    const int lane = t & 63;
    const int w = t >> 6;          // 0..3
    const int l15 = lane & 15;
    const int kg = lane >> 4;      // 0..3
    const int rb = blockIdx.x * 16;
    const int kb = w * 256;

    // ---------------- phase 1: asm burst-load x K-slice, then MFMA ---------
    const float* xp = x + (size_t)(rb + l15) * 1024 + kb + kg * 8;
    f32x4 xs[16];
#define XL(i, off) asm volatile("global_load_dwordx4 %0, %1, off offset:" #off \
                                : "=v"(xs[i]) : "v"(xp) : "memory")
    XL(0, 0);    XL(1, 16);   XL(2, 128);  XL(3, 144);
    XL(4, 256);  XL(5, 272);  XL(6, 384);  XL(7, 400);
    XL(8, 512);  XL(9, 528);  XL(10, 640); XL(11, 656);
    XL(12, 768); XL(13, 784); XL(14, 896); XL(15, 912);
#undef XL
    asm volatile("s_waitcnt vmcnt(0)" ::: "memory");
    __builtin_amdgcn_sched_barrier(0);   // rule 18: no consumer hoists above the wait

    f32x4 acc[4] = {{0.f, 0.f, 0.f, 0.f}, {0.f, 0.f, 0.f, 0.f},
                    {0.f, 0.f, 0.f, 0.f}, {0.f, 0.f, 0.f, 0.f}};
    const unsigned short* wp = WdT + l15 * 1024 + kb + kg * 8;
#pragma unroll
    for (int ks = 0; ks < 8; ++ks) {
        short8 b0 = *reinterpret_cast<const short8*>(wp + 0 * 16384 + ks * 32);
        short8 b1 = *reinterpret_cast<const short8*>(wp + 1 * 16384 + ks * 32);
        short8 b2 = *reinterpret_cast<const short8*>(wp + 2 * 16384 + ks * 32);
        short8 b3 = *reinterpret_cast<const short8*>(wp + 3 * 16384 + ks * 32);
        union { short8 v; unsigned short e[8]; } a;
        a.e[0] = f2bf(xs[2 * ks][0]); a.e[1] = f2bf(xs[2 * ks][1]);
        a.e[2] = f2bf(xs[2 * ks][2]); a.e[3] = f2bf(xs[2 * ks][3]);
        a.e[4] = f2bf(xs[2 * ks + 1][0]); a.e[5] = f2bf(xs[2 * ks + 1][1]);
        a.e[6] = f2bf(xs[2 * ks + 1][2]); a.e[7] = f2bf(xs[2 * ks + 1][3]);
        acc[0] = __builtin_amdgcn_mfma_f32_16x16x32_bf16(a.v, b0, acc[0], 0, 0, 0);
        acc[1] = __builtin_amdgcn_mfma_f32_16x16x32_bf16(a.v, b1, acc[1], 0, 0, 0);
        acc[2] = __builtin_amdgcn_mfma_f32_16x16x32_bf16(a.v, b2, acc[2], 0, 0, 0);
        acc[3] = __builtin_amdgcn_mfma_f32_16x16x32_bf16(a.v, b3, acc[3], 0, 0, 0);
    }
    // lane holds z[m=kg*4+r][j=ct*16+l15]; conflict-free b128 writes
#pragma unroll
    for (int ct = 0; ct < 4; ++ct)
        *reinterpret_cast<f32x4*>(&red[w][ct * 256 + lane * 4]) = acc[ct];
    __syncthreads();

    // ---------------- 4-way reduce + bias + relu -> bf16 zlds --------------
    {
        f32x4 v0 = *reinterpret_cast<const f32x4*>(&red[0][t * 4]);
        f32x4 v1 = *reinterpret_cast<const f32x4*>(&red[1][t * 4]);
        f32x4 v2 = *reinterpret_cast<const f32x4*>(&red[2][t * 4]);
        f32x4 v3 = *reinterpret_cast<const f32x4*>(&red[3][t * 4]);
        int ct = t >> 6, lane2 = t & 63;
        int colz = ct * 16 + (lane2 & 15);
        int rowz = (lane2 >> 4) * 4;
        float bdv = bd[colz];
#pragma unroll
        for (int r = 0; r < 4; ++r) {
            float zz = v0[r] + v1[r] + v2[r] + v3[r] + bdv;
            zz = zz > 0.f ? zz : 0.f;
            zlds[(rowz + r) * 80 + colz] = f2bf(zz);
        }
    }
    __syncthreads();

    // ---------------- phase 2: y^T-tile = WuT-frag x z-frag ----------------
    short8 az0 = *reinterpret_cast<const short8*>(zlds + l15 * 80 + kg * 8);
    short8 az1 = *reinterpret_cast<const short8*>(zlds + l15 * 80 + 32 + kg * 8);
    const size_t yb = (size_t)(rb + l15) * 1024;
#pragma unroll
    for (int half = 0; half < 2; ++half) {
        short8 wa[16];
#pragma unroll
        for (int i = 0; i < 8; ++i) {
            const int dbase = w * 256 + half * 128 + i * 16;
            const unsigned short* wup = WuT + (dbase + l15) * 64 + kg * 8;
            wa[2 * i]     = *reinterpret_cast<const short8*>(wup);
            wa[2 * i + 1] = *reinterpret_cast<const short8*>(wup + 32);
        }
        __builtin_amdgcn_sched_barrier(0);
#pragma unroll
        for (int i = 0; i < 8; ++i) {
            const int dbase = w * 256 + half * 128 + i * 16;
            f32x4 c = {0.f, 0.f, 0.f, 0.f};
            c = __builtin_amdgcn_mfma_f32_16x16x32_bf16(wa[2 * i], az0, c, 0, 0, 0);
            c = __builtin_amdgcn_mfma_f32_16x16x32_bf16(wa[2 * i + 1], az1, c, 0, 0, 0);
            f32x4 bv = *reinterpret_cast<const f32x4*>(bu + dbase + kg * 4);
            f32x4 o;
#pragma unroll
            for (int r = 0; r < 4; ++r) o[r] = c[r] + bv[r];
            *reinterpret_cast<f32x4*>(y + yb + dbase + kg * 4) = o;
        }
    }
}

extern "C" void kernel_launch(void* const* d_in, const int* in_sizes, int n_in,
                              void* d_out, int out_size, void* d_ws, size_t ws_size,
                              hipStream_t stream) {
    const float* x  = (const float*)d_in[0];
    const float* d1 = (const float*)d_in[1];
    const float* d2 = (const float*)d_in[2];
    const float* d3 = (const float*)d_in[3];
    const float* u1 = (const float*)d_in[4];
    const float* u2 = (const float*)d_in[5];
    const float* u3 = (const float*)d_in[6];
    const float* bd = (const float*)d_in[7];
    const float* bu = (const float*)d_in[8];
    float* y = (float*)d_out;
    unsigned short* WdT = (unsigned short*)d_ws;   // 64x1024 bf16
    unsigned short* WuT = WdT + 65536;             // 1024x64 bf16

    hipLaunchKernelGGL(tt_build_w_kernel, dim3(512), dim3(256), 0, stream,
                       d1, d2, d3, u1, u2, u3, WdT, WuT);
    hipLaunchKernelGGL(tt_main_kernel, dim3(1024), dim3(256), 0, stream,
                       x, WdT, WuT, bd, bu, y);
}

// Round 7
// 51.540 us; speedup vs baseline: 1.1268x; 1.1268x over previous
//
#include <hip/hip_runtime.h>

typedef float f32x2 __attribute__((ext_vector_type(2)));
typedef float f32x4 __attribute__((ext_vector_type(4)));
typedef short short8 __attribute__((ext_vector_type(8)));  // 8 x bf16 bits

static __device__ __forceinline__ unsigned short f2bf(float f) {
    __bf16 h = (__bf16)f;
    return __builtin_bit_cast(unsigned short, h);
}

// ---------------------------------------------------------------------------
// Kernel A: contract TT cores into dense TRANSPOSED bf16 weights.
//   WdT[j][i] = Wd[i][j],  j in [0,64)  (z-col), i in [0,1024) (x-dim)
//   WuT[d][k] = Wu[k][d],  d in [0,1024) (y-col), k in [0,64)  (z-dim)
// ---------------------------------------------------------------------------
__global__ __launch_bounds__(256) void tt_build_w_kernel(
    const float* __restrict__ d1, const float* __restrict__ d2, const float* __restrict__ d3,
    const float* __restrict__ u1, const float* __restrict__ u2, const float* __restrict__ u3,
    unsigned short* __restrict__ WdT, unsigned short* __restrict__ WuT)
{
    int t = blockIdx.x * 256 + threadIdx.x;
    if (t < 65536) {
        int j = t >> 10, i = t & 1023;
        int i1 = i >> 7, i2 = (i >> 3) & 15, i3 = i & 7;
        int j1 = j >> 4, j2 = (j >> 2) & 3, j3 = j & 3;
        float t3[8];
#pragma unroll
        for (int b = 0; b < 8; ++b) t3[b] = d3[(b * 8 + i3) * 4 + j3];
        float wsum = 0.f;
#pragma unroll
        for (int a = 0; a < 8; ++a) {
            float va = d1[(i1 * 4 + j1) * 8 + a];
            const float* p2 = d2 + ((a * 16 + i2) * 4 + j2) * 8;
            float wa = 0.f;
#pragma unroll
            for (int b = 0; b < 8; ++b) wa = fmaf(p2[b], t3[b], wa);
            wsum = fmaf(va, wa, wsum);
        }
        WdT[j * 1024 + i] = f2bf(wsum);
    } else {
        int t2 = t - 65536;
        int d = t2 >> 6, k = t2 & 63;
        int k1 = k >> 4, k2 = (k >> 2) & 3, k3 = k & 3;
        int o1 = d >> 7, o2 = (d >> 3) & 15, o3 = d & 7;
        float t3[8];
#pragma unroll
        for (int b = 0; b < 8; ++b) t3[b] = u3[(b * 4 + k3) * 8 + o3];
        float wsum = 0.f;
#pragma unroll
        for (int a = 0; a < 8; ++a) {
            float va = u1[(k1 * 8 + o1) * 8 + a];
            const float* p2 = u2 + ((a * 4 + k2) * 16 + o2) * 8;
            float wa = 0.f;
#pragma unroll
            for (int b = 0; b < 8; ++b) wa = fmaf(p2[b], t3[b], wa);
            wsum = fmaf(va, wa, wsum);
        }
        WuT[d * 64 + k] = f2bf(wsum);
    }
}

// asm burst: 16 global_load_dwordx4 pinned (cannot be sunk/shrunk) ----------
#define XBURST(dst, ptr)                                                                     \
    do {                                                                                     \
        asm volatile("global_load_dwordx4 %0, %1, off offset:0"   : "=v"(dst[0])  : "v"(ptr) : "memory"); \
        asm volatile("global_load_dwordx4 %0, %1, off offset:16"  : "=v"(dst[1])  : "v"(ptr) : "memory"); \
        asm volatile("global_load_dwordx4 %0, %1, off offset:128" : "=v"(dst[2])  : "v"(ptr) : "memory"); \
        asm volatile("global_load_dwordx4 %0, %1, off offset:144" : "=v"(dst[3])  : "v"(ptr) : "memory"); \
        asm volatile("global_load_dwordx4 %0, %1, off offset:256" : "=v"(dst[4])  : "v"(ptr) : "memory"); \
        asm volatile("global_load_dwordx4 %0, %1, off offset:272" : "=v"(dst[5])  : "v"(ptr) : "memory"); \
        asm volatile("global_load_dwordx4 %0, %1, off offset:384" : "=v"(dst[6])  : "v"(ptr) : "memory"); \
        asm volatile("global_load_dwordx4 %0, %1, off offset:400" : "=v"(dst[7])  : "v"(ptr) : "memory"); \
        asm volatile("global_load_dwordx4 %0, %1, off offset:512" : "=v"(dst[8])  : "v"(ptr) : "memory"); \
        asm volatile("global_load_dwordx4 %0, %1, off offset:528" : "=v"(dst[9])  : "v"(ptr) : "memory"); \
        asm volatile("global_load_dwordx4 %0, %1, off offset:640" : "=v"(dst[10]) : "v"(ptr) : "memory"); \
        asm volatile("global_load_dwordx4 %0, %1, off offset:656" : "=v"(dst[11]) : "v"(ptr) : "memory"); \
        asm volatile("global_load_dwordx4 %0, %1, off offset:768" : "=v"(dst[12]) : "v"(ptr) : "memory"); \
        asm volatile("global_load_dwordx4 %0, %1, off offset:784" : "=v"(dst[13]) : "v"(ptr) : "memory"); \
        asm volatile("global_load_dwordx4 %0, %1, off offset:896" : "=v"(dst[14]) : "v"(ptr) : "memory"); \
        asm volatile("global_load_dwordx4 %0, %1, off offset:912" : "=v"(dst[15]) : "v"(ptr) : "memory"); \
    } while (0)

static __device__ __forceinline__ void mfma_ktile(
    const f32x4 (&xs)[16], const unsigned short* __restrict__ wp, f32x4 (&acc)[4])
{
#pragma unroll
    for (int ks = 0; ks < 8; ++ks) {
        short8 b0 = *reinterpret_cast<const short8*>(wp + 0 * 16384 + ks * 32);
        short8 b1 = *reinterpret_cast<const short8*>(wp + 1 * 16384 + ks * 32);
        short8 b2 = *reinterpret_cast<const short8*>(wp + 2 * 16384 + ks * 32);
        short8 b3 = *reinterpret_cast<const short8*>(wp + 3 * 16384 + ks * 32);
        union { short8 v; unsigned short e[8]; } a;
        a.e[0] = f2bf(xs[2 * ks][0]); a.e[1] = f2bf(xs[2 * ks][1]);
        a.e[2] = f2bf(xs[2 * ks][2]); a.e[3] = f2bf(xs[2 * ks][3]);
        a.e[4] = f2bf(xs[2 * ks + 1][0]); a.e[5] = f2bf(xs[2 * ks + 1][1]);
        a.e[6] = f2bf(xs[2 * ks + 1][2]); a.e[7] = f2bf(xs[2 * ks + 1][3]);
        acc[0] = __builtin_amdgcn_mfma_f32_16x16x32_bf16(a.v, b0, acc[0], 0, 0, 0);
        acc[1] = __builtin_amdgcn_mfma_f32_16x16x32_bf16(a.v, b1, acc[1], 0, 0, 0);
        acc[2] = __builtin_amdgcn_mfma_f32_16x16x32_bf16(a.v, b2, acc[2], 0, 0, 0);
        acc[3] = __builtin_amdgcn_mfma_f32_16x16x32_bf16(a.v, b3, acc[3], 0, 0, 0);
    }
}

// ---------------------------------------------------------------------------
// K1: z = relu(x @ Wd + bd) as bf16 into zbuf[tile][row16][col64].
// Block = 256 thr (4 waves), processes 2 consecutive 16-row tiles with a
// cross-tile pipeline: tile t+1's 16-load asm burst issues BEFORE tile t's
// reduce/barrier phase, so HBM reads stay posted during the LDS work.
// Wave w owns K quarter [256w, +256). bd preloaded at top (no VMEM loads
// between burst and its consume except WdT, which precedes the burst).
// ---------------------------------------------------------------------------
__global__ __launch_bounds__(256) void tt_gemm1_kernel(
    const float* __restrict__ x, const unsigned short* __restrict__ WdT,
    const float* __restrict__ bd, unsigned short* __restrict__ zbuf)
{
    __shared__ float red[4][1024];
    const int t = threadIdx.x;
    const int lane = t & 63;
    const int w = t >> 6;
    const int l15 = lane & 15;
    const int kg = lane >> 4;
    const int kb = w * 256;
    const int tile0 = blockIdx.x * 2;

    // reduce-thread constants (loaded once; keeps VMEM out of reduce phase)
    const int ctz = t >> 6, lane2 = t & 63;
    const int colz = ctz * 16 + (lane2 & 15);
    const int rowz = (lane2 >> 4) * 4;
    const float bdv = bd[colz];

    const unsigned short* wp = WdT + l15 * 1024 + kb + kg * 8;
    const float* xp0 = x + (size_t)(tile0 * 16 + l15) * 1024 + kb + kg * 8;
    const float* xp1 = xp0 + 16 * 1024;

    f32x4 xs0[16], xs1[16];
    XBURST(xs0, xp0);

    // ------------------------------ tile 0 ---------------------------------
    asm volatile("s_waitcnt vmcnt(0)" ::: "memory");
    __builtin_amdgcn_sched_barrier(0);
    f32x4 acc[4] = {{0.f, 0.f, 0.f, 0.f}, {0.f, 0.f, 0.f, 0.f},
                    {0.f, 0.f, 0.f, 0.f}, {0.f, 0.f, 0.f, 0.f}};
    mfma_ktile(xs0, wp, acc);

    XBURST(xs1, xp1);   // tile1 reads in flight across the whole LDS phase

#pragma unroll
    for (int ct = 0; ct < 4; ++ct)
        *reinterpret_cast<f32x4*>(&red[w][ct * 256 + lane * 4]) = acc[ct];
    __syncthreads();
    {
        f32x4 v0 = *reinterpret_cast<const f32x4*>(&red[0][t * 4]);
        f32x4 v1 = *reinterpret_cast<const f32x4*>(&red[1][t * 4]);
        f32x4 v2 = *reinterpret_cast<const f32x4*>(&red[2][t * 4]);
        f32x4 v3 = *reinterpret_cast<const f32x4*>(&red[3][t * 4]);
#pragma unroll
        for (int r = 0; r < 4; ++r) {
            float zz = v0[r] + v1[r] + v2[r] + v3[r] + bdv;
            zz = zz > 0.f ? zz : 0.f;
            zbuf[tile0 * 1024 + (rowz + r) * 64 + colz] = f2bf(zz);
        }
    }
    __syncthreads();    // red reusable

    // ------------------------------ tile 1 ---------------------------------
    asm volatile("s_waitcnt vmcnt(0)" ::: "memory");
    __builtin_amdgcn_sched_barrier(0);
    f32x4 acc1[4] = {{0.f, 0.f, 0.f, 0.f}, {0.f, 0.f, 0.f, 0.f},
                     {0.f, 0.f, 0.f, 0.f}, {0.f, 0.f, 0.f, 0.f}};
    mfma_ktile(xs1, wp, acc1);
#pragma unroll
    for (int ct = 0; ct < 4; ++ct)
        *reinterpret_cast<f32x4*>(&red[w][ct * 256 + lane * 4]) = acc1[ct];
    __syncthreads();
    {
        f32x4 v0 = *reinterpret_cast<const f32x4*>(&red[0][t * 4]);
        f32x4 v1 = *reinterpret_cast<const f32x4*>(&red[1][t * 4]);
        f32x4 v2 = *reinterpret_cast<const f32x4*>(&red[2][t * 4]);
        f32x4 v3 = *reinterpret_cast<const f32x4*>(&red[3][t * 4]);
#pragma unroll
        for (int r = 0; r < 4; ++r) {
            float zz = v0[r] + v1[r] + v2[r] + v3[r] + bdv;
            zz = zz > 0.f ? zz : 0.f;
            zbuf[(tile0 + 1) * 1024 + (rowz + r) * 64 + colz] = f2bf(zz);
        }
    }
}

// ---------------------------------------------------------------------------
// K2: y = z @ Wu + bu. Pure write-stream. Block = 256 thr (4 waves); block
// (rg, ch) covers rows [rg*64, +64) x cols [ch*512, +512). WuT col-half
// (512 rows x 64 k = 64 KB) staged to LDS with XOR swizzle
// (chunk idx ^ ((idx>>3)&7)) so the col-slice b128 reads hit the 8-phase
// structural floor instead of 16-way conflicts. Bias in registers. Swapped
// MFMA (A=WuT-frag, B=z-frag, verified r5/r6) -> dwordx4 y stores.
// ---------------------------------------------------------------------------
__global__ __launch_bounds__(256) void tt_gemm2_kernel(
    const unsigned short* __restrict__ zbuf, const unsigned short* __restrict__ WuT,
    const float* __restrict__ bu, float* __restrict__ y)
{
    __shared__ unsigned short wlds[512 * 64];   // 64 KB
    const int t = threadIdx.x;
    const int lane = t & 63;
    const int w = t >> 6;
    const int l15 = lane & 15;
    const int kg = lane >> 4;
    const int ch = blockIdx.x & 1;
    const int rg = blockIdx.x >> 1;

    // stage WuT half (4096 x 16B chunks, swizzled destination)
    const unsigned short* src = WuT + ch * 512 * 64;
#pragma unroll
    for (int i = 0; i < 16; ++i) {
        int idx = i * 256 + t;
        int dst = idx ^ ((idx >> 3) & 7);
        *reinterpret_cast<short8*>(&wlds[dst * 8]) =
            *reinterpret_cast<const short8*>(src + idx * 8);
    }
    // bias preload: wave w covers cols ch*512 + w*128 + [0,128)
    f32x4 bv[8];
#pragma unroll
    for (int i = 0; i < 8; ++i)
        bv[i] = *reinterpret_cast<const f32x4*>(bu + ch * 512 + w * 128 + i * 16 + kg * 4);
    __syncthreads();

#pragma unroll
    for (int tt = 0; tt < 4; ++tt) {
        const int tile = rg * 4 + tt;
        short8 az0 = *reinterpret_cast<const short8*>(zbuf + tile * 1024 + l15 * 64 + kg * 8);
        short8 az1 = *reinterpret_cast<const short8*>(zbuf + tile * 1024 + l15 * 64 + 32 + kg * 8);
        const size_t yb = (size_t)(tile * 16 + l15) * 1024 + ch * 512 + w * 128;
#pragma unroll
        for (int i = 0; i < 8; ++i) {
            const int row = w * 128 + i * 16 + l15;     // local WuT row
            const int s = row & 7;
            short8 b0 = *reinterpret_cast<const short8*>(&wlds[(row * 8 + (kg ^ s)) * 8]);
            short8 b1 = *reinterpret_cast<const short8*>(&wlds[(row * 8 + ((kg + 4) ^ s)) * 8]);
            f32x4 c = {0.f, 0.f, 0.f, 0.f};
            c = __builtin_amdgcn_mfma_f32_16x16x32_bf16(b0, az0, c, 0, 0, 0);
            c = __builtin_amdgcn_mfma_f32_16x16x32_bf16(b1, az1, c, 0, 0, 0);
            f32x4 o;
#pragma unroll
            for (int r = 0; r < 4; ++r) o[r] = c[r] + bv[i][r];
            // lane holds y[tile*16+l15][i*16 + kg*4 + r]
            *reinterpret_cast<f32x4*>(y + yb + i * 16 + kg * 4) = o;
        }
    }
}

extern "C" void kernel_launch(void* const* d_in, const int* in_sizes, int n_in,
                              void* d_out, int out_size, void* d_ws, size_t ws_size,
                              hipStream_t stream) {
    const float* x  = (const float*)d_in[0];
    const float* d1 = (const float*)d_in[1];
    const float* d2 = (const float*)d_in[2];
    const float* d3 = (const float*)d_in[3];
    const float* u1 = (const float*)d_in[4];
    const float* u2 = (const float*)d_in[5];
    const float* u3 = (const float*)d_in[6];
    const float* bd = (const float*)d_in[7];
    const float* bu = (const float*)d_in[8];
    float* y = (float*)d_out;
    unsigned short* WdT  = (unsigned short*)d_ws;   // 64x1024 bf16 (128 KB)
    unsigned short* WuT  = WdT + 65536;             // 1024x64 bf16 (128 KB)
    unsigned short* zbuf = WuT + 65536;             // 1024 tiles x 16 x 64 bf16 (2 MB)

    hipLaunchKernelGGL(tt_build_w_kernel, dim3(512), dim3(256), 0, stream,
                       d1, d2, d3, u1, u2, u3, WdT, WuT);
    hipLaunchKernelGGL(tt_gemm1_kernel, dim3(512), dim3(256), 0, stream,
                       x, WdT, bd, zbuf);
    hipLaunchKernelGGL(tt_gemm2_kernel, dim3(512), dim3(256), 0, stream,
                       zbuf, WuT, bu, y);
}

// Round 8
// 50.976 us; speedup vs baseline: 1.1393x; 1.0111x over previous
//
#include <hip/hip_runtime.h>

typedef float f32x2 __attribute__((ext_vector_type(2)));
typedef float f32x4 __attribute__((ext_vector_type(4)));
typedef short short8 __attribute__((ext_vector_type(8)));  // 8 x bf16 bits

static __device__ __forceinline__ unsigned short f2bf(float f) {
    __bf16 h = (__bf16)f;
    return __builtin_bit_cast(unsigned short, h);
}

// ---------------------------------------------------------------------------
// Kernel A: contract TT cores into dense TRANSPOSED bf16 weights.
//   WdT[j][i] = Wd[i][j],  j in [0,64)  (z-col), i in [0,1024) (x-dim)
//   WuT[d][k] = Wu[k][d],  d in [0,1024) (y-col), k in [0,64)  (z-dim)
// ---------------------------------------------------------------------------
__global__ __launch_bounds__(256) void tt_build_w_kernel(
    const float* __restrict__ d1, const float* __restrict__ d2, const float* __restrict__ d3,
    const float* __restrict__ u1, const float* __restrict__ u2, const float* __restrict__ u3,
    unsigned short* __restrict__ WdT, unsigned short* __restrict__ WuT)
{
    int t = blockIdx.x * 256 + threadIdx.x;
    if (t < 65536) {
        int j = t >> 10, i = t & 1023;
        int i1 = i >> 7, i2 = (i >> 3) & 15, i3 = i & 7;
        int j1 = j >> 4, j2 = (j >> 2) & 3, j3 = j & 3;
        float t3[8];
#pragma unroll
        for (int b = 0; b < 8; ++b) t3[b] = d3[(b * 8 + i3) * 4 + j3];
        float wsum = 0.f;
#pragma unroll
        for (int a = 0; a < 8; ++a) {
            float va = d1[(i1 * 4 + j1) * 8 + a];
            const float* p2 = d2 + ((a * 16 + i2) * 4 + j2) * 8;
            float wa = 0.f;
#pragma unroll
            for (int b = 0; b < 8; ++b) wa = fmaf(p2[b], t3[b], wa);
            wsum = fmaf(va, wa, wsum);
        }
        WdT[j * 1024 + i] = f2bf(wsum);
    } else {
        int t2 = t - 65536;
        int d = t2 >> 6, k = t2 & 63;
        int k1 = k >> 4, k2 = (k >> 2) & 3, k3 = k & 3;
        int o1 = d >> 7, o2 = (d >> 3) & 15, o3 = d & 7;
        float t3[8];
#pragma unroll
        for (int b = 0; b < 8; ++b) t3[b] = u3[(b * 4 + k3) * 8 + o3];
        float wsum = 0.f;
#pragma unroll
        for (int a = 0; a < 8; ++a) {
            float va = u1[(k1 * 8 + o1) * 8 + a];
            const float* p2 = u2 + ((a * 4 + k2) * 16 + o2) * 8;
            float wa = 0.f;
#pragma unroll
            for (int b = 0; b < 8; ++b) wa = fmaf(p2[b], t3[b], wa);
            wsum = fmaf(va, wa, wsum);
        }
        WuT[d * 64 + k] = f2bf(wsum);
    }
}

// asm burst: 16 global_load_dwordx4 pinned (cannot be sunk/shrunk) ----------
#define XBURST(dst, ptr)                                                                     \
    do {                                                                                     \
        asm volatile("global_load_dwordx4 %0, %1, off offset:0"   : "=v"(dst[0])  : "v"(ptr) : "memory"); \
        asm volatile("global_load_dwordx4 %0, %1, off offset:16"  : "=v"(dst[1])  : "v"(ptr) : "memory"); \
        asm volatile("global_load_dwordx4 %0, %1, off offset:128" : "=v"(dst[2])  : "v"(ptr) : "memory"); \
        asm volatile("global_load_dwordx4 %0, %1, off offset:144" : "=v"(dst[3])  : "v"(ptr) : "memory"); \
        asm volatile("global_load_dwordx4 %0, %1, off offset:256" : "=v"(dst[4])  : "v"(ptr) : "memory"); \
        asm volatile("global_load_dwordx4 %0, %1, off offset:272" : "=v"(dst[5])  : "v"(ptr) : "memory"); \
        asm volatile("global_load_dwordx4 %0, %1, off offset:384" : "=v"(dst[6])  : "v"(ptr) : "memory"); \
        asm volatile("global_load_dwordx4 %0, %1, off offset:400" : "=v"(dst[7])  : "v"(ptr) : "memory"); \
        asm volatile("global_load_dwordx4 %0, %1, off offset:512" : "=v"(dst[8])  : "v"(ptr) : "memory"); \
        asm volatile("global_load_dwordx4 %0, %1, off offset:528" : "=v"(dst[9])  : "v"(ptr) : "memory"); \
        asm volatile("global_load_dwordx4 %0, %1, off offset:640" : "=v"(dst[10]) : "v"(ptr) : "memory"); \
        asm volatile("global_load_dwordx4 %0, %1, off offset:656" : "=v"(dst[11]) : "v"(ptr) : "memory"); \
        asm volatile("global_load_dwordx4 %0, %1, off offset:768" : "=v"(dst[12]) : "v"(ptr) : "memory"); \
        asm volatile("global_load_dwordx4 %0, %1, off offset:784" : "=v"(dst[13]) : "v"(ptr) : "memory"); \
        asm volatile("global_load_dwordx4 %0, %1, off offset:896" : "=v"(dst[14]) : "v"(ptr) : "memory"); \
        asm volatile("global_load_dwordx4 %0, %1, off offset:912" : "=v"(dst[15]) : "v"(ptr) : "memory"); \
    } while (0)

static __device__ __forceinline__ void mfma_ktile(
    const f32x4 (&xs)[16], const unsigned short* __restrict__ wp, f32x4 (&acc)[4])
{
#pragma unroll
    for (int ks = 0; ks < 8; ++ks) {
        short8 b0 = *reinterpret_cast<const short8*>(wp + 0 * 16384 + ks * 32);
        short8 b1 = *reinterpret_cast<const short8*>(wp + 1 * 16384 + ks * 32);
        short8 b2 = *reinterpret_cast<const short8*>(wp + 2 * 16384 + ks * 32);
        short8 b3 = *reinterpret_cast<const short8*>(wp + 3 * 16384 + ks * 32);
        union { short8 v; unsigned short e[8]; } a;
        a.e[0] = f2bf(xs[2 * ks][0]); a.e[1] = f2bf(xs[2 * ks][1]);
        a.e[2] = f2bf(xs[2 * ks][2]); a.e[3] = f2bf(xs[2 * ks][3]);
        a.e[4] = f2bf(xs[2 * ks + 1][0]); a.e[5] = f2bf(xs[2 * ks + 1][1]);
        a.e[6] = f2bf(xs[2 * ks + 1][2]); a.e[7] = f2bf(xs[2 * ks + 1][3]);
        acc[0] = __builtin_amdgcn_mfma_f32_16x16x32_bf16(a.v, b0, acc[0], 0, 0, 0);
        acc[1] = __builtin_amdgcn_mfma_f32_16x16x32_bf16(a.v, b1, acc[1], 0, 0, 0);
        acc[2] = __builtin_amdgcn_mfma_f32_16x16x32_bf16(a.v, b2, acc[2], 0, 0, 0);
        acc[3] = __builtin_amdgcn_mfma_f32_16x16x32_bf16(a.v, b3, acc[3], 0, 0, 0);
    }
}

// ---------------------------------------------------------------------------
// K1: z = relu(x @ Wd + bd) as bf16 into zbuf[tile][row16][col64].
// 1024 blocks x 256 thr (4 waves), ONE 16-row tile per block, K-split 4.
// One pinned 16-load burst per wave (16 KB in flight), launch_bounds(256,4)
// caps VGPR at 128 -> 4 blocks/CU, 16 waves/CU: cross-BLOCK overlap hides
// the burst wait and barrier phases (r7 had only 8 waves/CU).
// ---------------------------------------------------------------------------
__global__ __launch_bounds__(256, 4) void tt_gemm1_kernel(
    const float* __restrict__ x, const unsigned short* __restrict__ WdT,
    const float* __restrict__ bd, unsigned short* __restrict__ zbuf)
{
    __shared__ float red[4][1024];
    const int t = threadIdx.x;
    const int lane = t & 63;
    const int w = t >> 6;
    const int l15 = lane & 15;
    const int kg = lane >> 4;
    const int kb = w * 256;
    const int tile = blockIdx.x;

    const float* xp = x + (size_t)(tile * 16 + l15) * 1024 + kb + kg * 8;
    f32x4 xs[16];
    XBURST(xs, xp);

    // reduce-phase constants (issued after burst; covered by the same wait)
    const int colz = (t >> 6) * 16 + (t & 15);
    const int rowz = ((t & 63) >> 4) * 4;
    const float bdv = bd[colz];
    const unsigned short* wp = WdT + l15 * 1024 + kb + kg * 8;

    asm volatile("s_waitcnt vmcnt(0)" ::: "memory");
    __builtin_amdgcn_sched_barrier(0);
    f32x4 acc[4] = {{0.f, 0.f, 0.f, 0.f}, {0.f, 0.f, 0.f, 0.f},
                    {0.f, 0.f, 0.f, 0.f}, {0.f, 0.f, 0.f, 0.f}};
    mfma_ktile(xs, wp, acc);

#pragma unroll
    for (int ct = 0; ct < 4; ++ct)
        *reinterpret_cast<f32x4*>(&red[w][ct * 256 + lane * 4]) = acc[ct];
    __syncthreads();
    {
        f32x4 v0 = *reinterpret_cast<const f32x4*>(&red[0][t * 4]);
        f32x4 v1 = *reinterpret_cast<const f32x4*>(&red[1][t * 4]);
        f32x4 v2 = *reinterpret_cast<const f32x4*>(&red[2][t * 4]);
        f32x4 v3 = *reinterpret_cast<const f32x4*>(&red[3][t * 4]);
#pragma unroll
        for (int r = 0; r < 4; ++r) {
            float zz = v0[r] + v1[r] + v2[r] + v3[r] + bdv;
            zz = zz > 0.f ? zz : 0.f;
            zbuf[tile * 1024 + (rowz + r) * 64 + colz] = f2bf(zz);
        }
    }
}

// ---------------------------------------------------------------------------
// K2: y = z @ Wu + bu. Pure write-stream. Block = 256 thr (4 waves); block
// (rg, ch) covers rows [rg*64, +64) x cols [ch*512, +512). WuT col-half
// (512 rows x 64 k = 64 KB) staged to LDS with XOR swizzle
// (chunk idx ^ ((idx>>3)&7)) so the col-slice b128 reads hit the 8-phase
// structural floor instead of 16-way conflicts. Bias in registers. Swapped
// MFMA (A=WuT-frag, B=z-frag, verified r5-r7) -> dwordx4 y stores.
// ---------------------------------------------------------------------------
__global__ __launch_bounds__(256) void tt_gemm2_kernel(
    const unsigned short* __restrict__ zbuf, const unsigned short* __restrict__ WuT,
    const float* __restrict__ bu, float* __restrict__ y)
{
    __shared__ unsigned short wlds[512 * 64];   // 64 KB
    const int t = threadIdx.x;
    const int lane = t & 63;
    const int w = t >> 6;
    const int l15 = lane & 15;
    const int kg = lane >> 4;
    const int ch = blockIdx.x & 1;
    const int rg = blockIdx.x >> 1;

    // stage WuT half (4096 x 16B chunks, swizzled destination)
    const unsigned short* src = WuT + ch * 512 * 64;
#pragma unroll
    for (int i = 0; i < 16; ++i) {
        int idx = i * 256 + t;
        int dst = idx ^ ((idx >> 3) & 7);
        *reinterpret_cast<short8*>(&wlds[dst * 8]) =
            *reinterpret_cast<const short8*>(src + idx * 8);
    }
    // bias preload: wave w covers cols ch*512 + w*128 + [0,128)
    f32x4 bv[8];
#pragma unroll
    for (int i = 0; i < 8; ++i)
        bv[i] = *reinterpret_cast<const f32x4*>(bu + ch * 512 + w * 128 + i * 16 + kg * 4);
    __syncthreads();

#pragma unroll
    for (int tt = 0; tt < 4; ++tt) {
        const int tile = rg * 4 + tt;
        short8 az0 = *reinterpret_cast<const short8*>(zbuf + tile * 1024 + l15 * 64 + kg * 8);
        short8 az1 = *reinterpret_cast<const short8*>(zbuf + tile * 1024 + l15 * 64 + 32 + kg * 8);
        const size_t yb = (size_t)(tile * 16 + l15) * 1024 + ch * 512 + w * 128;
#pragma unroll
        for (int i = 0; i < 8; ++i) {
            const int row = w * 128 + i * 16 + l15;     // local WuT row
            const int s = row & 7;
            short8 b0 = *reinterpret_cast<const short8*>(&wlds[(row * 8 + (kg ^ s)) * 8]);
            short8 b1 = *reinterpret_cast<const short8*>(&wlds[(row * 8 + ((kg + 4) ^ s)) * 8]);
            f32x4 c = {0.f, 0.f, 0.f, 0.f};
            c = __builtin_amdgcn_mfma_f32_16x16x32_bf16(b0, az0, c, 0, 0, 0);
            c = __builtin_amdgcn_mfma_f32_16x16x32_bf16(b1, az1, c, 0, 0, 0);
            f32x4 o;
#pragma unroll
            for (int r = 0; r < 4; ++r) o[r] = c[r] + bv[i][r];
            // lane holds y[tile*16+l15][i*16 + kg*4 + r]
            *reinterpret_cast<f32x4*>(y + yb + i * 16 + kg * 4) = o;
        }
    }
}

extern "C" void kernel_launch(void* const* d_in, const int* in_sizes, int n_in,
                              void* d_out, int out_size, void* d_ws, size_t ws_size,
                              hipStream_t stream) {
    const float* x  = (const float*)d_in[0];
    const float* d1 = (const float*)d_in[1];
    const float* d2 = (const float*)d_in[2];
    const float* d3 = (const float*)d_in[3];
    const float* u1 = (const float*)d_in[4];
    const float* u2 = (const float*)d_in[5];
    const float* u3 = (const float*)d_in[6];
    const float* bd = (const float*)d_in[7];
    const float* bu = (const float*)d_in[8];
    float* y = (float*)d_out;
    unsigned short* WdT  = (unsigned short*)d_ws;   // 64x1024 bf16 (128 KB)
    unsigned short* WuT  = WdT + 65536;             // 1024x64 bf16 (128 KB)
    unsigned short* zbuf = WuT + 65536;             // 1024 tiles x 16 x 64 bf16 (2 MB)

    hipLaunchKernelGGL(tt_build_w_kernel, dim3(512), dim3(256), 0, stream,
                       d1, d2, d3, u1, u2, u3, WdT, WuT);
    hipLaunchKernelGGL(tt_gemm1_kernel, dim3(1024), dim3(256), 0, stream,
                       x, WdT, bd, zbuf);
    hipLaunchKernelGGL(tt_gemm2_kernel, dim3(512), dim3(256), 0, stream,
                       zbuf, WuT, bu, y);
}

// Round 9
// 50.934 us; speedup vs baseline: 1.1402x; 1.0008x over previous
//
#include <hip/hip_runtime.h>

typedef float f32x2 __attribute__((ext_vector_type(2)));
typedef float f32x4 __attribute__((ext_vector_type(4)));
typedef short short8 __attribute__((ext_vector_type(8)));  // 8 x bf16 bits

static __device__ __forceinline__ unsigned short f2bf(float f) {
    __bf16 h = (__bf16)f;
    return __builtin_bit_cast(unsigned short, h);
}

// ---------------------------------------------------------------------------
// Kernel A: contract TT cores into dense TRANSPOSED bf16 weights.
//   WdT[j][pos(i)] = Wd[i][j]  with k-slot permutation pos() matching the
//   DENSE x load pattern in gemm1 (lane kg reads 4 contiguous floats at
//   kg*16B; global k = s*32 + h*16 + kg*4 + e lands in fragment slot
//   kg*8 + h*4 + e). Dot products are slot-permutation invariant as long
//   as A and B agree.
//   WuT[d][k] = Wu[k][d] (unpermuted; gemm2's z/WuT reads are kg-dense).
// ---------------------------------------------------------------------------
__global__ __launch_bounds__(256) void tt_build_w_kernel(
    const float* __restrict__ d1, const float* __restrict__ d2, const float* __restrict__ d3,
    const float* __restrict__ u1, const float* __restrict__ u2, const float* __restrict__ u3,
    unsigned short* __restrict__ WdT, unsigned short* __restrict__ WuT)
{
    int t = blockIdx.x * 256 + threadIdx.x;
    if (t < 65536) {
        int j = t >> 10, i = t & 1023;
        int i1 = i >> 7, i2 = (i >> 3) & 15, i3 = i & 7;
        int j1 = j >> 4, j2 = (j >> 2) & 3, j3 = j & 3;
        float t3[8];
#pragma unroll
        for (int b = 0; b < 8; ++b) t3[b] = d3[(b * 8 + i3) * 4 + j3];
        float wsum = 0.f;
#pragma unroll
        for (int a = 0; a < 8; ++a) {
            float va = d1[(i1 * 4 + j1) * 8 + a];
            const float* p2 = d2 + ((a * 16 + i2) * 4 + j2) * 8;
            float wa = 0.f;
#pragma unroll
            for (int b = 0; b < 8; ++b) wa = fmaf(p2[b], t3[b], wa);
            wsum = fmaf(va, wa, wsum);
        }
        // k-slot permutation: global k=i -> slot (i&~31) | (kg*8 + h*4 + e)
        int g = i & 31;
        int h = g >> 4, kgg = (g >> 2) & 3, e = g & 3;
        int pos = (i & ~31) | (kgg * 8 + h * 4 + e);
        WdT[j * 1024 + pos] = f2bf(wsum);
    } else {
        int t2 = t - 65536;
        int d = t2 >> 6, k = t2 & 63;
        int k1 = k >> 4, k2 = (k >> 2) & 3, k3 = k & 3;
        int o1 = d >> 7, o2 = (d >> 3) & 15, o3 = d & 7;
        float t3[8];
#pragma unroll
        for (int b = 0; b < 8; ++b) t3[b] = u3[(b * 4 + k3) * 8 + o3];
        float wsum = 0.f;
#pragma unroll
        for (int a = 0; a < 8; ++a) {
            float va = u1[(k1 * 8 + o1) * 8 + a];
            const float* p2 = u2 + ((a * 4 + k2) * 16 + o2) * 8;
            float wa = 0.f;
#pragma unroll
            for (int b = 0; b < 8; ++b) wa = fmaf(p2[b], t3[b], wa);
            wsum = fmaf(va, wa, wsum);
        }
        WuT[d * 64 + k] = f2bf(wsum);
    }
}

// asm burst: 16 pinned global_load_dwordx4, DENSE 64B sectors per row:
// offsets j*64, lane base kg*16B -> each instruction covers 16 rows x 64B
// fully contiguous (was 16B-on/16B-off half-sectors in r2-r8).
#define XBURST(dst, ptr)                                                                     \
    do {                                                                                     \
        asm volatile("global_load_dwordx4 %0, %1, off offset:0"   : "=v"(dst[0])  : "v"(ptr) : "memory"); \
        asm volatile("global_load_dwordx4 %0, %1, off offset:64"  : "=v"(dst[1])  : "v"(ptr) : "memory"); \
        asm volatile("global_load_dwordx4 %0, %1, off offset:128" : "=v"(dst[2])  : "v"(ptr) : "memory"); \
        asm volatile("global_load_dwordx4 %0, %1, off offset:192" : "=v"(dst[3])  : "v"(ptr) : "memory"); \
        asm volatile("global_load_dwordx4 %0, %1, off offset:256" : "=v"(dst[4])  : "v"(ptr) : "memory"); \
        asm volatile("global_load_dwordx4 %0, %1, off offset:320" : "=v"(dst[5])  : "v"(ptr) : "memory"); \
        asm volatile("global_load_dwordx4 %0, %1, off offset:384" : "=v"(dst[6])  : "v"(ptr) : "memory"); \
        asm volatile("global_load_dwordx4 %0, %1, off offset:448" : "=v"(dst[7])  : "v"(ptr) : "memory"); \
        asm volatile("global_load_dwordx4 %0, %1, off offset:512" : "=v"(dst[8])  : "v"(ptr) : "memory"); \
        asm volatile("global_load_dwordx4 %0, %1, off offset:576" : "=v"(dst[9])  : "v"(ptr) : "memory"); \
        asm volatile("global_load_dwordx4 %0, %1, off offset:640" : "=v"(dst[10]) : "v"(ptr) : "memory"); \
        asm volatile("global_load_dwordx4 %0, %1, off offset:704" : "=v"(dst[11]) : "v"(ptr) : "memory"); \
        asm volatile("global_load_dwordx4 %0, %1, off offset:768" : "=v"(dst[12]) : "v"(ptr) : "memory"); \
        asm volatile("global_load_dwordx4 %0, %1, off offset:832" : "=v"(dst[13]) : "v"(ptr) : "memory"); \
        asm volatile("global_load_dwordx4 %0, %1, off offset:896" : "=v"(dst[14]) : "v"(ptr) : "memory"); \
        asm volatile("global_load_dwordx4 %0, %1, off offset:960" : "=v"(dst[15]) : "v"(ptr) : "memory"); \
    } while (0)

// xs[2s] = h=0 chunk (slots kg*8+0..3), xs[2s+1] = h=1 chunk (slots kg*8+4..7)
static __device__ __forceinline__ void mfma_ktile(
    const f32x4 (&xs)[16], const unsigned short* __restrict__ wp, f32x4 (&acc)[4])
{
#pragma unroll
    for (int ks = 0; ks < 8; ++ks) {
        short8 b0 = *reinterpret_cast<const short8*>(wp + 0 * 16384 + ks * 32);
        short8 b1 = *reinterpret_cast<const short8*>(wp + 1 * 16384 + ks * 32);
        short8 b2 = *reinterpret_cast<const short8*>(wp + 2 * 16384 + ks * 32);
        short8 b3 = *reinterpret_cast<const short8*>(wp + 3 * 16384 + ks * 32);
        union { short8 v; unsigned short e[8]; } a;
        a.e[0] = f2bf(xs[2 * ks][0]); a.e[1] = f2bf(xs[2 * ks][1]);
        a.e[2] = f2bf(xs[2 * ks][2]); a.e[3] = f2bf(xs[2 * ks][3]);
        a.e[4] = f2bf(xs[2 * ks + 1][0]); a.e[5] = f2bf(xs[2 * ks + 1][1]);
        a.e[6] = f2bf(xs[2 * ks + 1][2]); a.e[7] = f2bf(xs[2 * ks + 1][3]);
        acc[0] = __builtin_amdgcn_mfma_f32_16x16x32_bf16(a.v, b0, acc[0], 0, 0, 0);
        acc[1] = __builtin_amdgcn_mfma_f32_16x16x32_bf16(a.v, b1, acc[1], 0, 0, 0);
        acc[2] = __builtin_amdgcn_mfma_f32_16x16x32_bf16(a.v, b2, acc[2], 0, 0, 0);
        acc[3] = __builtin_amdgcn_mfma_f32_16x16x32_bf16(a.v, b3, acc[3], 0, 0, 0);
    }
}

// ---------------------------------------------------------------------------
// K1: z = relu(x @ Wd + bd) as bf16 into zbuf[tile][row16][col64].
// 1024 blocks x 256 thr (4 waves), one 16-row tile, K-split 4. One pinned
// 16-load DENSE burst per wave (16 KB in flight), LB(256,4) -> 16 waves/CU.
// ---------------------------------------------------------------------------
__global__ __launch_bounds__(256, 4) void tt_gemm1_kernel(
    const float* __restrict__ x, const unsigned short* __restrict__ WdT,
    const float* __restrict__ bd, unsigned short* __restrict__ zbuf)
{
    __shared__ float red[4][1024];
    const int t = threadIdx.x;
    const int lane = t & 63;
    const int w = t >> 6;
    const int l15 = lane & 15;
    const int kg = lane >> 4;
    const int kb = w * 256;
    const int tile = blockIdx.x;

    const float* xp = x + (size_t)(tile * 16 + l15) * 1024 + kb + kg * 4;  // DENSE base
    f32x4 xs[16];
    XBURST(xs, xp);

    // reduce-phase constants (issued after burst; covered by the same wait)
    const int colz = (t >> 6) * 16 + (t & 15);
    const int rowz = ((t & 63) >> 4) * 4;
    const float bdv = bd[colz];
    const unsigned short* wp = WdT + l15 * 1024 + kb + kg * 8;

    asm volatile("s_waitcnt vmcnt(0)" ::: "memory");
    __builtin_amdgcn_sched_barrier(0);
    f32x4 acc[4] = {{0.f, 0.f, 0.f, 0.f}, {0.f, 0.f, 0.f, 0.f},
                    {0.f, 0.f, 0.f, 0.f}, {0.f, 0.f, 0.f, 0.f}};
    mfma_ktile(xs, wp, acc);

#pragma unroll
    for (int ct = 0; ct < 4; ++ct)
        *reinterpret_cast<f32x4*>(&red[w][ct * 256 + lane * 4]) = acc[ct];
    __syncthreads();
    {
        f32x4 v0 = *reinterpret_cast<const f32x4*>(&red[0][t * 4]);
        f32x4 v1 = *reinterpret_cast<const f32x4*>(&red[1][t * 4]);
        f32x4 v2 = *reinterpret_cast<const f32x4*>(&red[2][t * 4]);
        f32x4 v3 = *reinterpret_cast<const f32x4*>(&red[3][t * 4]);
#pragma unroll
        for (int r = 0; r < 4; ++r) {
            float zz = v0[r] + v1[r] + v2[r] + v3[r] + bdv;
            zz = zz > 0.f ? zz : 0.f;
            zbuf[tile * 1024 + (rowz + r) * 64 + colz] = f2bf(zz);
        }
    }
}

// ---------------------------------------------------------------------------
// K2: y = z @ Wu + bu. Pure write-stream. Block = 256 thr (4 waves); block
// (rg, ch) covers rows [rg*64, +64) x cols [ch*512, +512). WuT col-half
// (64 KB) staged to LDS with XOR swizzle (chunk idx ^ ((idx>>3)&7)) ->
// balanced 8-phase b128 reads. Swapped MFMA -> dwordx4 y stores (dense).
// ---------------------------------------------------------------------------
__global__ __launch_bounds__(256) void tt_gemm2_kernel(
    const unsigned short* __restrict__ zbuf, const unsigned short* __restrict__ WuT,
    const float* __restrict__ bu, float* __restrict__ y)
{
    __shared__ unsigned short wlds[512 * 64];   // 64 KB
    const int t = threadIdx.x;
    const int lane = t & 63;
    const int w = t >> 6;
    const int l15 = lane & 15;
    const int kg = lane >> 4;
    const int ch = blockIdx.x & 1;
    const int rg = blockIdx.x >> 1;

    const unsigned short* src = WuT + ch * 512 * 64;
#pragma unroll
    for (int i = 0; i < 16; ++i) {
        int idx = i * 256 + t;
        int dst = idx ^ ((idx >> 3) & 7);
        *reinterpret_cast<short8*>(&wlds[dst * 8]) =
            *reinterpret_cast<const short8*>(src + idx * 8);
    }
    f32x4 bv[8];
#pragma unroll
    for (int i = 0; i < 8; ++i)
        bv[i] = *reinterpret_cast<const f32x4*>(bu + ch * 512 + w * 128 + i * 16 + kg * 4);
    __syncthreads();

#pragma unroll
    for (int tt = 0; tt < 4; ++tt) {
        const int tile = rg * 4 + tt;
        short8 az0 = *reinterpret_cast<const short8*>(zbuf + tile * 1024 + l15 * 64 + kg * 8);
        short8 az1 = *reinterpret_cast<const short8*>(zbuf + tile * 1024 + l15 * 64 + 32 + kg * 8);
        const size_t yb = (size_t)(tile * 16 + l15) * 1024 + ch * 512 + w * 128;
#pragma unroll
        for (int i = 0; i < 8; ++i) {
            const int row = w * 128 + i * 16 + l15;
            const int s = row & 7;
            short8 b0 = *reinterpret_cast<const short8*>(&wlds[(row * 8 + (kg ^ s)) * 8]);
            short8 b1 = *reinterpret_cast<const short8*>(&wlds[(row * 8 + ((kg + 4) ^ s)) * 8]);
            f32x4 c = {0.f, 0.f, 0.f, 0.f};
            c = __builtin_amdgcn_mfma_f32_16x16x32_bf16(b0, az0, c, 0, 0, 0);
            c = __builtin_amdgcn_mfma_f32_16x16x32_bf16(b1, az1, c, 0, 0, 0);
            f32x4 o;
#pragma unroll
            for (int r = 0; r < 4; ++r) o[r] = c[r] + bv[i][r];
            *reinterpret_cast<f32x4*>(y + yb + i * 16 + kg * 4) = o;
        }
    }
}

extern "C" void kernel_launch(void* const* d_in, const int* in_sizes, int n_in,
                              void* d_out, int out_size, void* d_ws, size_t ws_size,
                              hipStream_t stream) {
    const float* x  = (const float*)d_in[0];
    const float* d1 = (const float*)d_in[1];
    const float* d2 = (const float*)d_in[2];
    const float* d3 = (const float*)d_in[3];
    const float* u1 = (const float*)d_in[4];
    const float* u2 = (const float*)d_in[5];
    const float* u3 = (const float*)d_in[6];
    const float* bd = (const float*)d_in[7];
    const float* bu = (const float*)d_in[8];
    float* y = (float*)d_out;
    unsigned short* WdT  = (unsigned short*)d_ws;   // 64x1024 bf16 (128 KB)
    unsigned short* WuT  = WdT + 65536;             // 1024x64 bf16 (128 KB)
    unsigned short* zbuf = WuT + 65536;             // 1024 tiles x 16 x 64 bf16 (2 MB)

    hipLaunchKernelGGL(tt_build_w_kernel, dim3(512), dim3(256), 0, stream,
                       d1, d2, d3, u1, u2, u3, WdT, WuT);
    hipLaunchKernelGGL(tt_gemm1_kernel, dim3(1024), dim3(256), 0, stream,
                       x, WdT, bd, zbuf);
    hipLaunchKernelGGL(tt_gemm2_kernel, dim3(512), dim3(256), 0, stream,
                       zbuf, WuT, bu, y);
}